// Round 1
// baseline (8719.684 us; speedup 1.0000x reference)
//
#include <hip/hip_runtime.h>
#include <hip/hip_bf16.h>

// ---------------- problem constants ----------------
constexpr int B_   = 8;
constexpr int NP   = 32768;       // point nodes
constexpr int NFE  = 131072;      // feature nodes
constexpr int GCN  = 128;
constexpr int EDG  = 2000000;     // total edges
constexpr int NE   = 1000000;     // edges per direction
constexpr float LN_EPS = 1e-5f;

__device__ inline void fma4(float4& a, float s, const float4& w) {
    a.x = fmaf(s, w.x, a.x); a.y = fmaf(s, w.y, a.y);
    a.z = fmaf(s, w.z, a.z); a.w = fmaf(s, w.w, a.w);
}
__device__ inline float4 ld4(const float* p) { return *(const float4*)p; }

// ---------------- projections ----------------
// xp3 = x_p @ w_pd.T + b_pd   : (8,12288)@(12288,12288) -> flat (8*12288)
// block handles 4 output cols (one per wave), 8 batch rows each.
__global__ __launch_bounds__(256) void proj_p_k(const float* __restrict__ x_p,
                                                const float* __restrict__ w_pd,
                                                const float* __restrict__ b_pd,
                                                float* __restrict__ out) {
    const int j = blockIdx.x * 4 + (threadIdx.x >> 6);
    const int l = threadIdx.x & 63;
    float acc[8] = {0,0,0,0,0,0,0,0};
    const float* wrow = w_pd + (size_t)j * 12288;
    for (int kk = l * 4; kk < 12288; kk += 256) {
        float4 wv = ld4(wrow + kk);
        #pragma unroll
        for (int b = 0; b < 8; ++b) {
            float4 xv = ld4(x_p + b * 12288 + kk);
            acc[b] += wv.x*xv.x + wv.y*xv.y + wv.z*xv.z + wv.w*xv.w;
        }
    }
    #pragma unroll
    for (int b = 0; b < 8; ++b)
        for (int off = 32; off; off >>= 1)
            acc[b] += __shfl_down(acc[b], off);
    if (l == 0) {
        float bj = b_pd[j];
        #pragma unroll
        for (int b = 0; b < 8; ++b) out[b * 12288 + j] = acc[b] + bj;
    }
}

// xf3 = x_f @ w_fd.T + b_fd : (2048,64)@(64,192) -> flat (2048*192)
__global__ __launch_bounds__(256) void proj_f_k(const float* __restrict__ x_f,
                                                const float* __restrict__ w_fd,
                                                const float* __restrict__ b_fd,
                                                float* __restrict__ out) {
    const int id = blockIdx.x * 256 + threadIdx.x;   // 2048*192 outputs
    const int j = id % 192, f = id / 192;
    float acc = b_fd[j];
    const float* xr = x_f + f * 64;
    const float* wr = w_fd + j * 64;
    for (int k = 0; k < 64; k += 4) {
        float4 xv = ld4(xr + k), wv = ld4(wr + k);
        acc += xv.x*wv.x + xv.y*wv.y + xv.z*wv.z + xv.w*wv.w;
    }
    out[id] = acc;
}

// ---------------- weight transposes (wT[k][j] = w[j][k]) ----------------
struct TransJob { const float* src; float* dst; int K; };
struct TransArgs { TransJob jobs[10]; };
__global__ __launch_bounds__(256) void transpose_k(TransArgs a) {
    TransJob jb = a.jobs[blockIdx.y];
    int id = blockIdx.x * 256 + threadIdx.x;
    if (id >= 128 * jb.K) return;
    int j = id % 128, k = id / 128;
    jb.dst[k * 128 + j] = jb.src[j * jb.K + k];
}

// ---------------- degree counts ----------------
__global__ __launch_bounds__(256) void count_deg_k(const int* __restrict__ ei,
                                                   float* __restrict__ cnt) {
    int e = blockIdx.x * 256 + threadIdx.x;
    if (e >= EDG) return;
    if ((e & 1) == 0) atomicAdd(&cnt[ei[EDG + e]], 1.f);        // even: dst = row1 -> point
    else              atomicAdd(&cnt[NP + ei[e]], 1.f);         // odd : dst = row0 -> feature
}
__global__ __launch_bounds__(256) void inv_deg_k(float* __restrict__ cnt) {
    int i = blockIdx.x * 256 + threadIdx.x;
    if (i < NP + NFE) cnt[i] = 1.f / fmaxf(cnt[i], 1.f);
}

// ---------------- scatter (segment-sum via atomics) ----------------
// src_base/dst_base indexed at [2e]
__global__ __launch_bounds__(256) void scatter3_k(const int* __restrict__ src_base,
                                                  const int* __restrict__ dst_base,
                                                  const float* __restrict__ feat,
                                                  float* __restrict__ agg) {
    int e = blockIdx.x * 256 + threadIdx.x;
    if (e >= NE) return;
    int s = src_base[2 * e], d = dst_base[2 * e];
    atomicAdd(&agg[d * 3 + 0], feat[s * 3 + 0]);
    atomicAdd(&agg[d * 3 + 1], feat[s * 3 + 1]);
    atomicAdd(&agg[d * 3 + 2], feat[s * 3 + 2]);
}
__global__ __launch_bounds__(256) void scatter128_k(const int* __restrict__ src_base,
                                                    const int* __restrict__ dst_base,
                                                    const float* __restrict__ feat,
                                                    float* __restrict__ agg) {
    int gid = blockIdx.x * 256 + threadIdx.x;
    int e = gid >> 5, cg = gid & 31;
    if (e >= NE) return;
    int s = src_base[2 * e], d = dst_base[2 * e];
    float4 v = ld4(feat + (size_t)s * 128 + cg * 4);
    float* ap = agg + (size_t)d * 128 + cg * 4;
    atomicAdd(ap + 0, v.x); atomicAdd(ap + 1, v.y);
    atomicAdd(ap + 2, v.z); atomicAdd(ap + 3, v.w);
}

// ---------------- sage combine: out = relu(mean(agg)@wlT + bl + dst@wrT) ----------------
template<int K1, int K2>
__global__ __launch_bounds__(256) void combine_k(const float* __restrict__ agg,
                                                 const float* __restrict__ inv,
                                                 const float* __restrict__ dstf,
                                                 const float* __restrict__ wlT,
                                                 const float* __restrict__ wrT,
                                                 const float* __restrict__ bias,
                                                 float* __restrict__ out) {
    __shared__ float a1[32][K1];
    __shared__ float a2[32][K2];
    const int node0 = blockIdx.x * 32;
    for (int i = threadIdx.x; i < 32 * K1; i += 256) {
        int n = i / K1, k = i - n * K1;
        a1[n][k] = agg[(size_t)(node0 + n) * K1 + k] * inv[node0 + n];
    }
    for (int i = threadIdx.x; i < 32 * K2; i += 256) {
        int n = i / K2, k = i - n * K2;
        a2[n][k] = dstf[(size_t)(node0 + n) * K2 + k];
    }
    __syncthreads();
    const int jg = threadIdx.x & 31, ng = threadIdx.x >> 5;
    const int j0 = jg * 4, n0 = ng * 4;
    float4 acc[4] = {};
    // mat1 (agg-side)
    if constexpr (K1 % 4 == 0) {
        for (int k0 = 0; k0 < K1; k0 += 4) {
            float4 w0 = ld4(wlT + (k0+0)*128 + j0);
            float4 w1 = ld4(wlT + (k0+1)*128 + j0);
            float4 w2 = ld4(wlT + (k0+2)*128 + j0);
            float4 w3 = ld4(wlT + (k0+3)*128 + j0);
            #pragma unroll
            for (int i = 0; i < 4; ++i) {
                float4 av = *(const float4*)&a1[n0+i][k0];
                fma4(acc[i], av.x, w0); fma4(acc[i], av.y, w1);
                fma4(acc[i], av.z, w2); fma4(acc[i], av.w, w3);
            }
        }
    } else {
        #pragma unroll
        for (int k = 0; k < K1; ++k) {
            float4 wv = ld4(wlT + k*128 + j0);
            #pragma unroll
            for (int i = 0; i < 4; ++i) fma4(acc[i], a1[n0+i][k], wv);
        }
    }
    // mat2 (dst-side)
    if constexpr (K2 % 4 == 0) {
        for (int k0 = 0; k0 < K2; k0 += 4) {
            float4 w0 = ld4(wrT + (k0+0)*128 + j0);
            float4 w1 = ld4(wrT + (k0+1)*128 + j0);
            float4 w2 = ld4(wrT + (k0+2)*128 + j0);
            float4 w3 = ld4(wrT + (k0+3)*128 + j0);
            #pragma unroll
            for (int i = 0; i < 4; ++i) {
                float4 av = *(const float4*)&a2[n0+i][k0];
                fma4(acc[i], av.x, w0); fma4(acc[i], av.y, w1);
                fma4(acc[i], av.z, w2); fma4(acc[i], av.w, w3);
            }
        }
    } else {
        #pragma unroll
        for (int k = 0; k < K2; ++k) {
            float4 wv = ld4(wrT + k*128 + j0);
            #pragma unroll
            for (int i = 0; i < 4; ++i) fma4(acc[i], a2[n0+i][k], wv);
        }
    }
    float4 bv = ld4(bias + j0);
    #pragma unroll
    for (int i = 0; i < 4; ++i) {
        float4 r;
        r.x = fmaxf(acc[i].x + bv.x, 0.f); r.y = fmaxf(acc[i].y + bv.y, 0.f);
        r.z = fmaxf(acc[i].z + bv.z, 0.f); r.w = fmaxf(acc[i].w + bv.w, 0.f);
        *(float4*)&out[(size_t)(node0 + n0 + i) * 128 + j0] = r;
    }
}

// ---------------- layernorm (in-place, row = 128) ----------------
__global__ __launch_bounds__(256) void ln_k(float* __restrict__ x, int M,
                                            const float* __restrict__ g,
                                            const float* __restrict__ b) {
    int row = blockIdx.x * 4 + (threadIdx.x >> 6);
    int l = threadIdx.x & 63;
    if (row >= M) return;
    float* xr = x + (size_t)row * 128;
    float v0 = xr[l], v1 = xr[l + 64];
    float s = v0 + v1;
    for (int off = 32; off; off >>= 1) s += __shfl_xor(s, off);
    float m = s * (1.f / 128.f);
    float d0 = v0 - m, d1 = v1 - m;
    float q = d0 * d0 + d1 * d1;
    for (int off = 32; off; off >>= 1) q += __shfl_xor(q, off);
    float rs = rsqrtf(q * (1.f / 128.f) + LN_EPS);
    xr[l]      = d0 * rs * g[l]      + b[l];
    xr[l + 64] = d1 * rs * g[l + 64] + b[l + 64];
}

// ---------------- conv1d (k=8, VALID, oc=64) ----------------
template<int IC>
__global__ __launch_bounds__(256) void conv1d_k(const float* __restrict__ x,
                                                const float* __restrict__ w,
                                                const float* __restrict__ bias,
                                                float* __restrict__ out,
                                                int Lin, int Lout) {
    __shared__ float xs[IC * 72];
    const int b = blockIdx.y;
    const int p0t = blockIdx.x * 64;
    for (int i = threadIdx.x; i < IC * 72; i += 256) {
        int ic = i / 72, pos = i - ic * 72;
        int gp = p0t + pos;
        xs[i] = (pos < 71 && gp < Lin) ? x[((size_t)(b * IC + ic)) * Lin + gp] : 0.f;
    }
    __syncthreads();
    const int oc = threadIdx.x & 63;
    const int pg = threadIdx.x >> 6;      // 0..3, 16 positions each
    const int pbase = pg * 16;
    float acc[16];
    #pragma unroll
    for (int p = 0; p < 16; ++p) acc[p] = 0.f;
    for (int ic = 0; ic < IC; ++ic) {
        float xw[24];
        const float* xr = &xs[ic * 72 + pbase];
        #pragma unroll
        for (int q = 0; q < 6; ++q) {
            float4 v = *(const float4*)(xr + q * 4);
            xw[q*4+0] = v.x; xw[q*4+1] = v.y; xw[q*4+2] = v.z; xw[q*4+3] = v.w;
        }
        float4 w0 = ld4(w + ((size_t)(oc * IC + ic)) * 8);
        float4 w1 = ld4(w + ((size_t)(oc * IC + ic)) * 8 + 4);
        float wk[8] = {w0.x, w0.y, w0.z, w0.w, w1.x, w1.y, w1.z, w1.w};
        #pragma unroll
        for (int k = 0; k < 8; ++k)
            #pragma unroll
            for (int p = 0; p < 16; ++p)
                acc[p] = fmaf(wk[k], xw[p + k], acc[p]);
    }
    float bo = bias[oc];
    const int pout0 = p0t + pbase;
    #pragma unroll
    for (int p = 0; p < 16; ++p) {
        int po = pout0 + p;
        if (po < Lout) out[((size_t)(b * 64 + oc)) * Lout + po] = fmaxf(acc[p] + bo, 0.f);
    }
}

// ---------------- fc1 partial (atomic accumulate, no bias) ----------------
__global__ __launch_bounds__(256) void fc1_k(const float* __restrict__ x,
                                             const float* __restrict__ w,
                                             float* __restrict__ fc1) {
    const int j = blockIdx.x >> 4;
    const int c = blockIdx.x & 15;
    const int start = c * 16300;
    float acc[8] = {0,0,0,0,0,0,0,0};
    for (int i = start + threadIdx.x * 4; i < start + 16300; i += 1024) {
        float4 wv = ld4(w + (size_t)j * 260800 + i);
        #pragma unroll
        for (int b = 0; b < 8; ++b) {
            float4 xv = ld4(x + (size_t)b * 260800 + i);
            acc[b] += wv.x*xv.x + wv.y*xv.y + wv.z*xv.z + wv.w*xv.w;
        }
    }
    __shared__ float red[8][257];
    #pragma unroll
    for (int b = 0; b < 8; ++b) red[b][threadIdx.x] = acc[b];
    __syncthreads();
    for (int off = 128; off; off >>= 1) {
        if (threadIdx.x < off)
            #pragma unroll
            for (int b = 0; b < 8; ++b)
                red[b][threadIdx.x] += red[b][threadIdx.x + off];
        __syncthreads();
    }
    if (threadIdx.x < 8) atomicAdd(&fc1[threadIdx.x * 100 + j], red[threadIdx.x][0]);
}

// ---------------- head: relu(fc1+b1) @ d2w.T + d2b -> softmax ----------------
__global__ __launch_bounds__(64) void head_k(const float* __restrict__ fc1,
                                             const float* __restrict__ d1b,
                                             const float* __restrict__ d2w,
                                             const float* __restrict__ d2b,
                                             float* __restrict__ out) {
    int b = threadIdx.x;
    if (b >= 8) return;
    float l0 = d2b[0], l1 = d2b[1];
    for (int j = 0; j < 100; ++j) {
        float h = fmaxf(fc1[b * 100 + j] + d1b[j], 0.f);
        l0 = fmaf(h, d2w[j], l0);
        l1 = fmaf(h, d2w[100 + j], l1);
    }
    float m = fmaxf(l0, l1);
    float e0 = expf(l0 - m), e1 = expf(l1 - m);
    float inv = 1.f / (e0 + e1);
    out[b * 2 + 0] = e0 * inv;
    out[b * 2 + 1] = e1 * inv;
}

// ---------------- launcher ----------------
extern "C" void kernel_launch(void* const* d_in, const int* in_sizes, int n_in,
                              void* d_out, int out_size, void* d_ws, size_t ws_size,
                              hipStream_t stream) {
    const float* x_p   = (const float*)d_in[0];
    const float* x_f   = (const float*)d_in[1];
    const int*   ei    = (const int*)d_in[2];
    const float* w_pd  = (const float*)d_in[3];
    const float* b_pd  = (const float*)d_in[4];
    const float* w_fd  = (const float*)d_in[5];
    const float* b_fd  = (const float*)d_in[6];
    const float* wl1_0 = (const float*)d_in[7];
    const float* bl1_0 = (const float*)d_in[8];
    const float* wr1_0 = (const float*)d_in[9];
    const float* wl1_1 = (const float*)d_in[10];
    const float* bl1_1 = (const float*)d_in[11];
    const float* wr1_1 = (const float*)d_in[12];
    const float* wl1_2 = (const float*)d_in[13];
    const float* bl1_2 = (const float*)d_in[14];
    const float* wr1_2 = (const float*)d_in[15];
    const float* wl2_0 = (const float*)d_in[16];
    const float* bl2_0 = (const float*)d_in[17];
    const float* wr2_0 = (const float*)d_in[18];
    const float* wl2_1 = (const float*)d_in[19];
    const float* bl2_1 = (const float*)d_in[20];
    const float* wr2_1 = (const float*)d_in[21];
    // wl2_2 / bl2_2 / wr2_2 (22..24) are dead: final output uses only xp.
    const float* ln_g  = (const float*)d_in[25];
    const float* ln_b  = (const float*)d_in[26];
    const float* cw1   = (const float*)d_in[27];
    const float* cb1   = (const float*)d_in[28];
    const float* cw2   = (const float*)d_in[29];
    const float* cb2   = (const float*)d_in[30];
    const float* cw3   = (const float*)d_in[31];
    const float* cb3   = (const float*)d_in[32];
    const float* d1w   = (const float*)d_in[33];
    const float* d1b   = (const float*)d_in[34];
    const float* d2w   = (const float*)d_in[35];
    const float* d2b   = (const float*)d_in[36];

    float* ws  = (float*)d_ws;
    float* xp  = ws;                       // NP*128      = 4,194,304
    float* xf  = xp  + 4194304;            // NFE*128     = 16,777,216
    float* agg = xf  + 16777216;           // max(NP,NFE)*128 = 16,777,216
    float* xp3 = agg + 16777216;           // NP*3
    float* xf3 = xp3 + 98304;              // NFE*3
    float* cnt = xf3 + 393216;             // NP + NFE  (becomes inv-degree)
    float* wT  = cnt + 163840;             // 10 * 16384
    // conv & fc buffers overlap agg (agg dead after last combine)
    float* c1  = agg;                      // 8*64*4089
    float* c2  = c1 + 2093568;             // 8*64*4082
    float* c3  = c2 + 2089984;             // 8*64*4075
    float* fc1 = c3 + 2086400;             // 800
    float* inv_p = cnt;
    float* inv_f = cnt + NP;

    // degree counts
    hipMemsetAsync(cnt, 0, (size_t)(NP + NFE) * 4, stream);
    count_deg_k<<<(EDG + 255) / 256, 256, 0, stream>>>(ei, cnt);
    inv_deg_k<<<(NP + NFE) / 256, 256, 0, stream>>>(cnt);

    // weight transposes
    TransArgs ta;
    ta.jobs[0] = {wl1_0, wT + 0 * 16384, 3};
    ta.jobs[1] = {wr1_0, wT + 1 * 16384, 3};
    ta.jobs[2] = {wl1_1, wT + 2 * 16384, 128};
    ta.jobs[3] = {wr1_1, wT + 3 * 16384, 128};
    ta.jobs[4] = {wl1_2, wT + 4 * 16384, 128};
    ta.jobs[5] = {wr1_2, wT + 5 * 16384, 128};
    ta.jobs[6] = {wl2_0, wT + 6 * 16384, 128};
    ta.jobs[7] = {wr2_0, wT + 7 * 16384, 3};
    ta.jobs[8] = {wl2_1, wT + 8 * 16384, 128};
    ta.jobs[9] = {wr2_1, wT + 9 * 16384, 128};
    transpose_k<<<dim3(64, 10), 256, 0, stream>>>(ta);

    // projections
    proj_p_k<<<12288 / 4, 256, 0, stream>>>(x_p, w_pd, b_pd, xp3);
    proj_f_k<<<(2048 * 192) / 256, 256, 0, stream>>>(x_f, w_fd, b_fd, xf3);

    // edge index views: fp uses even columns, pf uses odd columns reversed
    const int* fp_src = ei;            // [2e]     -> row0 even (feature id)
    const int* fp_dst = ei + EDG;      // [2e]     -> row1 even (point id)
    const int* pf_src = ei + EDG + 1;  // [2e]     -> row1 odd  (point id)
    const int* pf_dst = ei + 1;        // [2e]     -> row0 odd  (feature id)

    // ---- round 0 ----
    hipMemsetAsync(agg, 0, (size_t)NP * 3 * 4, stream);
    scatter3_k<<<(NE + 255) / 256, 256, 0, stream>>>(fp_src, fp_dst, xf3, agg);
    combine_k<3, 3><<<NP / 32, 256, 0, stream>>>(agg, inv_p, xp3, wT + 0 * 16384, wT + 1 * 16384, bl1_0, xp);

    hipMemsetAsync(agg, 0, (size_t)NFE * 128 * 4, stream);
    scatter128_k<<<(NE * 32) / 256, 256, 0, stream>>>(pf_src, pf_dst, xp, agg);
    combine_k<128, 3><<<NFE / 32, 256, 0, stream>>>(agg, inv_f, xf3, wT + 6 * 16384, wT + 7 * 16384, bl2_0, xf);

    ln_k<<<NP / 4, 256, 0, stream>>>(xp, NP, ln_g, ln_b);
    ln_k<<<NFE / 4, 256, 0, stream>>>(xf, NFE, ln_g, ln_b);

    // ---- round 1 ----
    hipMemsetAsync(agg, 0, (size_t)NP * 128 * 4, stream);
    scatter128_k<<<(NE * 32) / 256, 256, 0, stream>>>(fp_src, fp_dst, xf, agg);
    combine_k<128, 128><<<NP / 32, 256, 0, stream>>>(agg, inv_p, xp, wT + 2 * 16384, wT + 3 * 16384, bl1_1, xp);

    hipMemsetAsync(agg, 0, (size_t)NFE * 128 * 4, stream);
    scatter128_k<<<(NE * 32) / 256, 256, 0, stream>>>(pf_src, pf_dst, xp, agg);
    combine_k<128, 128><<<NFE / 32, 256, 0, stream>>>(agg, inv_f, xf, wT + 8 * 16384, wT + 9 * 16384, bl2_1, xf);

    ln_k<<<NP / 4, 256, 0, stream>>>(xp, NP, ln_g + 128, ln_b + 128);
    ln_k<<<NFE / 4, 256, 0, stream>>>(xf, NFE, ln_g + 128, ln_b + 128);

    // ---- round 2 (pf side is dead code, skipped) ----
    hipMemsetAsync(agg, 0, (size_t)NP * 128 * 4, stream);
    scatter128_k<<<(NE * 32) / 256, 256, 0, stream>>>(fp_src, fp_dst, xf, agg);
    combine_k<128, 128><<<NP / 32, 256, 0, stream>>>(agg, inv_p, xp, wT + 4 * 16384, wT + 5 * 16384, bl1_2, xp);

    // ---- convs: xp viewed as (8,128,4096) ----
    conv1d_k<128><<<dim3(64, 8), 256, 0, stream>>>(xp, cw1, cb1, c1, 4096, 4089);
    conv1d_k<64><<<dim3(64, 8), 256, 0, stream>>>(c1, cw2, cb2, c2, 4089, 4082);
    conv1d_k<64><<<dim3(64, 8), 256, 0, stream>>>(c2, cw3, cb3, c3, 4082, 4075);

    // ---- dense head ----
    hipMemsetAsync(fc1, 0, 800 * 4, stream);
    fc1_k<<<100 * 16, 256, 0, stream>>>(c3, d1w, fc1);
    head_k<<<1, 64, 0, stream>>>(fc1, d1b, d2w, d2b, (float*)d_out);
}

// Round 3
// 2300.438 us; speedup vs baseline: 3.7904x; 3.7904x over previous
//
#include <hip/hip_runtime.h>
#include <hip/hip_bf16.h>

// ---------------- problem constants ----------------
constexpr int B_   = 8;
constexpr int NP   = 32768;       // point nodes
constexpr int NFE  = 131072;      // feature nodes
constexpr int GCN  = 128;
constexpr int EDG  = 2000000;     // total edges
constexpr int NE   = 1000000;     // edges per direction
constexpr float LN_EPS = 1e-5f;

__device__ inline void fma4(float4& a, float s, const float4& w) {
    a.x = fmaf(s, w.x, a.x); a.y = fmaf(s, w.y, a.y);
    a.z = fmaf(s, w.z, a.z); a.w = fmaf(s, w.w, a.w);
}
__device__ inline float4 ld4(const float* p) { return *(const float4*)p; }

// ---------------- projections ----------------
__global__ __launch_bounds__(256) void proj_p_k(const float* __restrict__ x_p,
                                                const float* __restrict__ w_pd,
                                                const float* __restrict__ b_pd,
                                                float* __restrict__ out) {
    const int j = blockIdx.x * 4 + (threadIdx.x >> 6);
    const int l = threadIdx.x & 63;
    float acc[8] = {0,0,0,0,0,0,0,0};
    const float* wrow = w_pd + (size_t)j * 12288;
    for (int kk = l * 4; kk < 12288; kk += 256) {
        float4 wv = ld4(wrow + kk);
        #pragma unroll
        for (int b = 0; b < 8; ++b) {
            float4 xv = ld4(x_p + b * 12288 + kk);
            acc[b] += wv.x*xv.x + wv.y*xv.y + wv.z*xv.z + wv.w*xv.w;
        }
    }
    #pragma unroll
    for (int b = 0; b < 8; ++b)
        for (int off = 32; off; off >>= 1)
            acc[b] += __shfl_down(acc[b], off);
    if (l == 0) {
        float bj = b_pd[j];
        #pragma unroll
        for (int b = 0; b < 8; ++b) out[b * 12288 + j] = acc[b] + bj;
    }
}

__global__ __launch_bounds__(256) void proj_f_k(const float* __restrict__ x_f,
                                                const float* __restrict__ w_fd,
                                                const float* __restrict__ b_fd,
                                                float* __restrict__ out) {
    const int id = blockIdx.x * 256 + threadIdx.x;   // 2048*192 outputs
    const int j = id % 192, f = id / 192;
    float acc = b_fd[j];
    const float* xr = x_f + f * 64;
    const float* wr = w_fd + j * 64;
    for (int k = 0; k < 64; k += 4) {
        float4 xv = ld4(xr + k), wv = ld4(wr + k);
        acc += xv.x*wv.x + xv.y*wv.y + xv.z*wv.z + xv.w*wv.w;
    }
    out[id] = acc;
}

// ---------------- weight transposes ----------------
struct TransJob { const float* src; float* dst; int K; };
struct TransArgs { TransJob jobs[10]; };
__global__ __launch_bounds__(256) void transpose_k(TransArgs a) {
    TransJob jb = a.jobs[blockIdx.y];
    int id = blockIdx.x * 256 + threadIdx.x;
    if (id >= 128 * jb.K) return;
    int j = id % 128, k = id / 128;
    jb.dst[k * 128 + j] = jb.src[j * jb.K + k];
}

// ---------------- CSR build ----------------
__global__ __launch_bounds__(256) void deg_k(const int* __restrict__ ei,
                                             int* __restrict__ deg_p,
                                             int* __restrict__ deg_f) {
    int e = blockIdx.x * 256 + threadIdx.x;
    if (e >= NE) return;
    atomicAdd(&deg_p[ei[EDG + 2 * e]], 1);   // fp dst (row1, even cols)
    atomicAdd(&deg_f[ei[1 + 2 * e]], 1);     // pf dst (row0, odd cols)
}

// exclusive scan, phase A: per-256-block
__global__ __launch_bounds__(256) void scanA_k(const int* __restrict__ in,
                                               int* __restrict__ out,
                                               int* __restrict__ bsums, int n) {
    __shared__ int tmp[256];
    int gid = blockIdx.x * 256 + threadIdx.x;
    int v = (gid < n) ? in[gid] : 0;
    tmp[threadIdx.x] = v;
    __syncthreads();
    for (int off = 1; off < 256; off <<= 1) {
        int t = (threadIdx.x >= off) ? tmp[threadIdx.x - off] : 0;
        __syncthreads();
        tmp[threadIdx.x] += t;
        __syncthreads();
    }
    if (gid < n) out[gid] = tmp[threadIdx.x] - v;
    if (threadIdx.x == 255) bsums[blockIdx.x] = tmp[255];
}
// phase B: exclusive scan of block sums (nb <= 512)
__global__ __launch_bounds__(256) void scanB_k(int* __restrict__ bsums, int nb) {
    __shared__ int tmp[512];
    for (int i = threadIdx.x; i < nb; i += 256) tmp[i] = bsums[i];
    __syncthreads();
    if (threadIdx.x == 0) {
        int acc = 0;
        for (int i = 0; i < nb; ++i) { int t = tmp[i]; tmp[i] = acc; acc += t; }
    }
    __syncthreads();
    for (int i = threadIdx.x; i < nb; i += 256) bsums[i] = tmp[i];
}
// phase C: add offsets, init cursor, compute inv-degree
__global__ __launch_bounds__(256) void scanC_k(int* __restrict__ starts,
                                               const int* __restrict__ bsums,
                                               const int* __restrict__ deg,
                                               int* __restrict__ cursor,
                                               float* __restrict__ inv, int n) {
    int gid = blockIdx.x * 256 + threadIdx.x;
    if (gid >= n) return;
    int s = starts[gid] + bsums[blockIdx.x];
    starts[gid] = s;
    cursor[gid] = s;
    inv[gid] = 1.f / fmaxf((float)deg[gid], 1.f);
}

__global__ __launch_bounds__(256) void build_k(const int* __restrict__ src_base,
                                               const int* __restrict__ dst_base,
                                               int* __restrict__ cursor,
                                               int* __restrict__ esrc) {
    int e = blockIdx.x * 256 + threadIdx.x;
    if (e >= NE) return;
    int pos = atomicAdd(&cursor[dst_base[2 * e]], 1);
    esrc[pos] = src_base[2 * e];
}

// ---------------- round-0 fp gather (3-wide) ----------------
__global__ __launch_bounds__(256) void gather3_k(const int* __restrict__ starts,
                                                 const int* __restrict__ ends,
                                                 const int* __restrict__ esrc,
                                                 const float* __restrict__ feat,
                                                 float* __restrict__ agg, int n) {
    int t = blockIdx.x * 256 + threadIdx.x;
    if (t >= n) return;
    int s0 = starts[t], s1 = ends[t];
    float a0 = 0, a1 = 0, a2 = 0;
    for (int e = s0; e < s1; ++e) {
        int s = esrc[e];
        a0 += feat[s * 3 + 0]; a1 += feat[s * 3 + 1]; a2 += feat[s * 3 + 2];
    }
    agg[t * 3 + 0] = a0; agg[t * 3 + 1] = a1; agg[t * 3 + 2] = a2;
}

// ---------------- unfused combine (K1=3 path, round 0 fp) ----------------
template<int K1, int K2>
__global__ __launch_bounds__(256) void combine_k(const float* __restrict__ agg,
                                                 const float* __restrict__ inv,
                                                 const float* __restrict__ dstf,
                                                 const float* __restrict__ wlT,
                                                 const float* __restrict__ wrT,
                                                 const float* __restrict__ bias,
                                                 float* __restrict__ out) {
    __shared__ float a1[32][K1];
    __shared__ float a2[32][K2];
    const int node0 = blockIdx.x * 32;
    for (int i = threadIdx.x; i < 32 * K1; i += 256) {
        int n = i / K1, k = i - n * K1;
        a1[n][k] = agg[(size_t)(node0 + n) * K1 + k] * inv[node0 + n];
    }
    for (int i = threadIdx.x; i < 32 * K2; i += 256) {
        int n = i / K2, k = i - n * K2;
        a2[n][k] = dstf[(size_t)(node0 + n) * K2 + k];
    }
    __syncthreads();
    const int jg = threadIdx.x & 31, ng = threadIdx.x >> 5;
    const int j0 = jg * 4, n0 = ng * 4;
    float4 acc[4] = {};
    #pragma unroll
    for (int k = 0; k < K1; ++k) {
        float4 wv = ld4(wlT + k * 128 + j0);
        #pragma unroll
        for (int i = 0; i < 4; ++i) fma4(acc[i], a1[n0 + i][k], wv);
    }
    #pragma unroll
    for (int k = 0; k < K2; ++k) {
        float4 wv = ld4(wrT + k * 128 + j0);
        #pragma unroll
        for (int i = 0; i < 4; ++i) fma4(acc[i], a2[n0 + i][k], wv);
    }
    float4 bv = ld4(bias + j0);
    #pragma unroll
    for (int i = 0; i < 4; ++i) {
        float4 r;
        r.x = fmaxf(acc[i].x + bv.x, 0.f); r.y = fmaxf(acc[i].y + bv.y, 0.f);
        r.z = fmaxf(acc[i].z + bv.z, 0.f); r.w = fmaxf(acc[i].w + bv.w, 0.f);
        *(float4*)&out[(size_t)(node0 + n0 + i) * 128 + j0] = r;
    }
}

// ---------------- fused gather + combine (K1 = 128) ----------------
// out[node] = relu( mean_gather(feat) @ wlT + bias + dstf[node] @ wrT )
template<int K2>
__global__ __launch_bounds__(256) void fused_combine_k(
        const int* __restrict__ starts, const int* __restrict__ ends,
        const int* __restrict__ esrc, const float* __restrict__ feat,
        const float* __restrict__ inv, const float* __restrict__ dstf,
        const float* __restrict__ wlT, const float* __restrict__ wrT,
        const float* __restrict__ bias, float* __restrict__ out) {
    __shared__ float a1[32][128];
    __shared__ float a2[32][K2];
    const int node0 = blockIdx.x * 32;
    const int w = threadIdx.x >> 6, l = threadIdx.x & 63;
    // gather phase: wave w produces a1 rows w*8 .. w*8+7 (mean of neighbors)
    for (int ni = 0; ni < 8; ++ni) {
        const int n = w * 8 + ni;
        const int node = node0 + n;
        const int s0 = starts[node], s1 = ends[node];
        float2 acc = {0.f, 0.f};
        for (int e0 = s0; e0 < s1; e0 += 64) {
            int my = (e0 + l < s1) ? esrc[e0 + l] : 0;
            int cnt = min(s1 - e0, 64);
            for (int i = 0; i < cnt; ++i) {
                int s = __shfl(my, i);
                float2 v = *(const float2*)(feat + (size_t)s * 128 + l * 2);
                acc.x += v.x; acc.y += v.y;
            }
        }
        float iv = inv[node];
        a1[n][l * 2]     = acc.x * iv;
        a1[n][l * 2 + 1] = acc.y * iv;
    }
    for (int i = threadIdx.x; i < 32 * K2; i += 256) {
        int n = i / K2, k = i - n * K2;
        a2[n][k] = dstf[(size_t)(node0 + n) * K2 + k];
    }
    __syncthreads();
    const int jg = threadIdx.x & 31, ng = threadIdx.x >> 5;
    const int j0 = jg * 4, n0 = ng * 4;
    float4 acc[4] = {};
    for (int k0 = 0; k0 < 128; k0 += 4) {
        float4 w0 = ld4(wlT + (k0+0)*128 + j0);
        float4 w1 = ld4(wlT + (k0+1)*128 + j0);
        float4 w2 = ld4(wlT + (k0+2)*128 + j0);
        float4 w3 = ld4(wlT + (k0+3)*128 + j0);
        #pragma unroll
        for (int i = 0; i < 4; ++i) {
            float4 av = *(const float4*)&a1[n0+i][k0];
            fma4(acc[i], av.x, w0); fma4(acc[i], av.y, w1);
            fma4(acc[i], av.z, w2); fma4(acc[i], av.w, w3);
        }
    }
    if constexpr (K2 % 4 == 0) {
        for (int k0 = 0; k0 < K2; k0 += 4) {
            float4 w0 = ld4(wrT + (k0+0)*128 + j0);
            float4 w1 = ld4(wrT + (k0+1)*128 + j0);
            float4 w2 = ld4(wrT + (k0+2)*128 + j0);
            float4 w3 = ld4(wrT + (k0+3)*128 + j0);
            #pragma unroll
            for (int i = 0; i < 4; ++i) {
                float4 av = *(const float4*)&a2[n0+i][k0];
                fma4(acc[i], av.x, w0); fma4(acc[i], av.y, w1);
                fma4(acc[i], av.z, w2); fma4(acc[i], av.w, w3);
            }
        }
    } else {
        #pragma unroll
        for (int k = 0; k < K2; ++k) {
            float4 wv = ld4(wrT + k * 128 + j0);
            #pragma unroll
            for (int i = 0; i < 4; ++i) fma4(acc[i], a2[n0+i][k], wv);
        }
    }
    float4 bv = ld4(bias + j0);
    #pragma unroll
    for (int i = 0; i < 4; ++i) {
        float4 r;
        r.x = fmaxf(acc[i].x + bv.x, 0.f); r.y = fmaxf(acc[i].y + bv.y, 0.f);
        r.z = fmaxf(acc[i].z + bv.z, 0.f); r.w = fmaxf(acc[i].w + bv.w, 0.f);
        *(float4*)&out[(size_t)(node0 + n0 + i) * 128 + j0] = r;
    }
}

// ---------------- layernorm (in-place, row = 128) ----------------
__global__ __launch_bounds__(256) void ln_k(float* __restrict__ x, int M,
                                            const float* __restrict__ g,
                                            const float* __restrict__ b) {
    int row = blockIdx.x * 4 + (threadIdx.x >> 6);
    int l = threadIdx.x & 63;
    if (row >= M) return;
    float* xr = x + (size_t)row * 128;
    float v0 = xr[l], v1 = xr[l + 64];
    float s = v0 + v1;
    for (int off = 32; off; off >>= 1) s += __shfl_xor(s, off);
    float m = s * (1.f / 128.f);
    float d0 = v0 - m, d1 = v1 - m;
    float q = d0 * d0 + d1 * d1;
    for (int off = 32; off; off >>= 1) q += __shfl_xor(q, off);
    float rs = rsqrtf(q * (1.f / 128.f) + LN_EPS);
    xr[l]      = d0 * rs * g[l]      + b[l];
    xr[l + 64] = d1 * rs * g[l + 64] + b[l + 64];
}

// ---------------- conv1d (k=8, VALID, oc=64) ----------------
template<int IC>
__global__ __launch_bounds__(256) void conv1d_k(const float* __restrict__ x,
                                                const float* __restrict__ w,
                                                const float* __restrict__ bias,
                                                float* __restrict__ out,
                                                int Lin, int Lout) {
    __shared__ float xs[IC * 72];
    const int b = blockIdx.y;
    const int p0t = blockIdx.x * 64;
    for (int i = threadIdx.x; i < IC * 72; i += 256) {
        int ic = i / 72, pos = i - ic * 72;
        int gp = p0t + pos;
        xs[i] = (pos < 71 && gp < Lin) ? x[((size_t)(b * IC + ic)) * Lin + gp] : 0.f;
    }
    __syncthreads();
    const int oc = threadIdx.x & 63;
    const int pg = threadIdx.x >> 6;
    const int pbase = pg * 16;
    float acc[16];
    #pragma unroll
    for (int p = 0; p < 16; ++p) acc[p] = 0.f;
    for (int ic = 0; ic < IC; ++ic) {
        float xw[24];
        const float* xr = &xs[ic * 72 + pbase];
        #pragma unroll
        for (int q = 0; q < 6; ++q) {
            float4 v = *(const float4*)(xr + q * 4);
            xw[q*4+0] = v.x; xw[q*4+1] = v.y; xw[q*4+2] = v.z; xw[q*4+3] = v.w;
        }
        float4 w0 = ld4(w + ((size_t)(oc * IC + ic)) * 8);
        float4 w1 = ld4(w + ((size_t)(oc * IC + ic)) * 8 + 4);
        float wk[8] = {w0.x, w0.y, w0.z, w0.w, w1.x, w1.y, w1.z, w1.w};
        #pragma unroll
        for (int k = 0; k < 8; ++k)
            #pragma unroll
            for (int p = 0; p < 16; ++p)
                acc[p] = fmaf(wk[k], xw[p + k], acc[p]);
    }
    float bo = bias[oc];
    const int pout0 = p0t + pbase;
    #pragma unroll
    for (int p = 0; p < 16; ++p) {
        int po = pout0 + p;
        if (po < Lout) out[((size_t)(b * 64 + oc)) * Lout + po] = fmaxf(acc[p] + bo, 0.f);
    }
}

// ---------------- fc1 partial ----------------
__global__ __launch_bounds__(256) void fc1_k(const float* __restrict__ x,
                                             const float* __restrict__ w,
                                             float* __restrict__ fc1) {
    const int j = blockIdx.x >> 4;
    const int c = blockIdx.x & 15;
    const int start = c * 16300;
    float acc[8] = {0,0,0,0,0,0,0,0};
    for (int i = start + threadIdx.x * 4; i < start + 16300; i += 1024) {
        float4 wv = ld4(w + (size_t)j * 260800 + i);
        #pragma unroll
        for (int b = 0; b < 8; ++b) {
            float4 xv = ld4(x + (size_t)b * 260800 + i);
            acc[b] += wv.x*xv.x + wv.y*xv.y + wv.z*xv.z + wv.w*xv.w;
        }
    }
    __shared__ float red[8][257];
    #pragma unroll
    for (int b = 0; b < 8; ++b) red[b][threadIdx.x] = acc[b];
    __syncthreads();
    for (int off = 128; off; off >>= 1) {
        if (threadIdx.x < off)
            #pragma unroll
            for (int b = 0; b < 8; ++b)
                red[b][threadIdx.x] += red[b][threadIdx.x + off];
        __syncthreads();
    }
    if (threadIdx.x < 8) atomicAdd(&fc1[threadIdx.x * 100 + j], red[threadIdx.x][0]);
}

// ---------------- head ----------------
__global__ __launch_bounds__(64) void head_k(const float* __restrict__ fc1,
                                             const float* __restrict__ d1b,
                                             const float* __restrict__ d2w,
                                             const float* __restrict__ d2b,
                                             float* __restrict__ out) {
    int b = threadIdx.x;
    if (b >= 8) return;
    float l0 = d2b[0], l1 = d2b[1];
    for (int j = 0; j < 100; ++j) {
        float h = fmaxf(fc1[b * 100 + j] + d1b[j], 0.f);
        l0 = fmaf(h, d2w[j], l0);
        l1 = fmaf(h, d2w[100 + j], l1);
    }
    float m = fmaxf(l0, l1);
    float e0 = expf(l0 - m), e1 = expf(l1 - m);
    float inv = 1.f / (e0 + e1);
    out[b * 2 + 0] = e0 * inv;
    out[b * 2 + 1] = e1 * inv;
}

// ---------------- launcher ----------------
extern "C" void kernel_launch(void* const* d_in, const int* in_sizes, int n_in,
                              void* d_out, int out_size, void* d_ws, size_t ws_size,
                              hipStream_t stream) {
    const float* x_p   = (const float*)d_in[0];
    const float* x_f   = (const float*)d_in[1];
    const int*   ei    = (const int*)d_in[2];
    const float* w_pd  = (const float*)d_in[3];
    const float* b_pd  = (const float*)d_in[4];
    const float* w_fd  = (const float*)d_in[5];
    const float* b_fd  = (const float*)d_in[6];
    const float* wl1_0 = (const float*)d_in[7];
    const float* bl1_0 = (const float*)d_in[8];
    const float* wr1_0 = (const float*)d_in[9];
    const float* wl1_1 = (const float*)d_in[10];
    const float* bl1_1 = (const float*)d_in[11];
    const float* wr1_1 = (const float*)d_in[12];
    const float* wl1_2 = (const float*)d_in[13];
    const float* bl1_2 = (const float*)d_in[14];
    const float* wr1_2 = (const float*)d_in[15];
    const float* wl2_0 = (const float*)d_in[16];
    const float* bl2_0 = (const float*)d_in[17];
    const float* wr2_0 = (const float*)d_in[18];
    const float* wl2_1 = (const float*)d_in[19];
    const float* bl2_1 = (const float*)d_in[20];
    const float* wr2_1 = (const float*)d_in[21];
    // wl2_2 / bl2_2 / wr2_2 (22..24) are dead: final output uses only xp.
    const float* ln_g  = (const float*)d_in[25];
    const float* ln_b  = (const float*)d_in[26];
    const float* cw1   = (const float*)d_in[27];
    const float* cb1   = (const float*)d_in[28];
    const float* cw2   = (const float*)d_in[29];
    const float* cb2   = (const float*)d_in[30];
    const float* cw3   = (const float*)d_in[31];
    const float* cb3   = (const float*)d_in[32];
    const float* d1w   = (const float*)d_in[33];
    const float* d1b   = (const float*)d_in[34];
    const float* d2w   = (const float*)d_in[35];
    const float* d2b   = (const float*)d_in[36];

    float* ws  = (float*)d_ws;
    float* xp   = ws;                      // 4,194,304  (NP*128)
    float* xf   = xp  + 4194304;           // 16,777,216 (NFE*128)
    float* xp3  = xf  + 16777216;          // 98,304
    float* xf3  = xp3 + 98304;             // 393,216
    float* agg3 = xf3 + 393216;            // 98,304 (NP*3)
    float* wT   = agg3 + 98304;            // 163,840
    float* invb = wT  + 163840;            // 163,840 float
    int* ib     = (int*)(invb + 163840);
    int* deg_p  = ib;                      // 32,768
    int* deg_f  = deg_p + NP;              // 131,072
    int* st_p   = deg_f + NFE;             // 32,768
    int* st_f   = st_p + NP;               // 131,072
    int* cur_p  = st_f + NFE;              // 32,768
    int* cur_f  = cur_p + NP;              // 131,072
    int* esrc_p = cur_f + NFE;             // 1,000,000
    int* esrc_f = esrc_p + NE;             // 1,000,000
    int* bsumP  = esrc_f + NE;             // 512
    int* bsumF  = bsumP + 512;             // 512
    float* inv_p = invb;
    float* inv_f = invb + NP;
    // conv/fc buffers overlap xf (dead after round-2 gather)
    float* c1  = xf;                       // 8*64*4089 = 2,093,568
    float* c2  = c1 + 2093568;             // 8*64*4082 = 2,089,984
    float* c3  = c2 + 2089984;             // 8*64*4075 = 2,086,400
    float* fc1 = c3 + 2086400;             // 800

    // ---- CSR build ----
    hipMemsetAsync(deg_p, 0, (size_t)(NP + NFE) * 4, stream);
    deg_k<<<(NE + 255) / 256, 256, 0, stream>>>(ei, deg_p, deg_f);
    scanA_k<<<NP / 256, 256, 0, stream>>>(deg_p, st_p, bsumP, NP);
    scanA_k<<<NFE / 256, 256, 0, stream>>>(deg_f, st_f, bsumF, NFE);
    scanB_k<<<1, 256, 0, stream>>>(bsumP, NP / 256);
    scanB_k<<<1, 256, 0, stream>>>(bsumF, NFE / 256);
    scanC_k<<<NP / 256, 256, 0, stream>>>(st_p, bsumP, deg_p, cur_p, inv_p, NP);
    scanC_k<<<NFE / 256, 256, 0, stream>>>(st_f, bsumF, deg_f, cur_f, inv_f, NFE);
    const int* fp_src = ei;            // [2e] row0 even (feature id)
    const int* fp_dst = ei + EDG;      // [2e] row1 even (point id)
    const int* pf_src = ei + EDG + 1;  // [2e] row1 odd  (point id)
    const int* pf_dst = ei + 1;        // [2e] row0 odd  (feature id)
    build_k<<<(NE + 255) / 256, 256, 0, stream>>>(fp_src, fp_dst, cur_p, esrc_p);
    build_k<<<(NE + 255) / 256, 256, 0, stream>>>(pf_src, pf_dst, cur_f, esrc_f);
    // after build_k, cur_* hold CSR row ends.

    // ---- weight transposes ----
    TransArgs ta;
    ta.jobs[0] = {wl1_0, wT + 0 * 16384, 3};
    ta.jobs[1] = {wr1_0, wT + 1 * 16384, 3};
    ta.jobs[2] = {wl1_1, wT + 2 * 16384, 128};
    ta.jobs[3] = {wr1_1, wT + 3 * 16384, 128};
    ta.jobs[4] = {wl1_2, wT + 4 * 16384, 128};
    ta.jobs[5] = {wr1_2, wT + 5 * 16384, 128};
    ta.jobs[6] = {wl2_0, wT + 6 * 16384, 128};
    ta.jobs[7] = {wr2_0, wT + 7 * 16384, 3};
    ta.jobs[8] = {wl2_1, wT + 8 * 16384, 128};
    ta.jobs[9] = {wr2_1, wT + 9 * 16384, 128};
    transpose_k<<<dim3(64, 10), 256, 0, stream>>>(ta);

    // ---- projections ----
    proj_p_k<<<12288 / 4, 256, 0, stream>>>(x_p, w_pd, b_pd, xp3);
    proj_f_k<<<(2048 * 192) / 256, 256, 0, stream>>>(x_f, w_fd, b_fd, xf3);

    // ---- round 0 ----
    gather3_k<<<NP / 256, 256, 0, stream>>>(st_p, cur_p, esrc_p, xf3, agg3, NP);
    combine_k<3, 3><<<NP / 32, 256, 0, stream>>>(agg3, inv_p, xp3, wT + 0 * 16384, wT + 1 * 16384, bl1_0, xp);
    fused_combine_k<3><<<NFE / 32, 256, 0, stream>>>(st_f, cur_f, esrc_f, xp, inv_f, xf3,
                                                     wT + 6 * 16384, wT + 7 * 16384, bl2_0, xf);
    ln_k<<<NP / 4, 256, 0, stream>>>(xp, NP, ln_g, ln_b);
    ln_k<<<NFE / 4, 256, 0, stream>>>(xf, NFE, ln_g, ln_b);

    // ---- round 1 ----
    fused_combine_k<128><<<NP / 32, 256, 0, stream>>>(st_p, cur_p, esrc_p, xf, inv_p, xp,
                                                      wT + 2 * 16384, wT + 3 * 16384, bl1_1, xp);
    fused_combine_k<128><<<NFE / 32, 256, 0, stream>>>(st_f, cur_f, esrc_f, xp, inv_f, xf,
                                                       wT + 8 * 16384, wT + 9 * 16384, bl2_1, xf);
    ln_k<<<NP / 4, 256, 0, stream>>>(xp, NP, ln_g + 128, ln_b + 128);
    ln_k<<<NFE / 4, 256, 0, stream>>>(xf, NFE, ln_g + 128, ln_b + 128);

    // ---- round 2 (pf side dead) ----
    fused_combine_k<128><<<NP / 32, 256, 0, stream>>>(st_p, cur_p, esrc_p, xf, inv_p, xp,
                                                      wT + 4 * 16384, wT + 5 * 16384, bl1_2, xp);

    // ---- convs: xp viewed as (8,128,4096) ----
    conv1d_k<128><<<dim3(64, 8), 256, 0, stream>>>(xp, cw1, cb1, c1, 4096, 4089);
    conv1d_k<64><<<dim3(64, 8), 256, 0, stream>>>(c1, cw2, cb2, c2, 4089, 4082);
    conv1d_k<64><<<dim3(64, 8), 256, 0, stream>>>(c2, cw3, cb3, c3, 4082, 4075);

    // ---- dense head ----
    hipMemsetAsync(fc1, 0, 800 * 4, stream);
    fc1_k<<<100 * 16, 256, 0, stream>>>(c3, d1w, fc1);
    head_k<<<1, 64, 0, stream>>>(fc1, d1b, d2w, d2b, (float*)d_out);
}